// Round 1
// baseline (7674.907 us; speedup 1.0000x reference)
//
#include <hip/hip_runtime.h>
#include <hip/hip_bf16.h>

#define NB   2048
#define NN0  111
#define NN1  56
#define NN2  28
#define FD   256
#define HD   128

// ---------------------------------------------------------------------------
// K1: stage-1 conv. One block per graph. h1[bl] = [relu(gcn)|relu(cheb)] (111x256)
// LDS: xs[111][112] + P[111][64] + U[111][64] + abits + dis  = 109,232 B
// ---------------------------------------------------------------------------
__global__ __launch_bounds__(512) void k_stage1(
    const float* __restrict__ x, const float* __restrict__ adj,
    const float* __restrict__ wg, const float* __restrict__ wsp,
    float* __restrict__ h1, int b0)
{
  extern __shared__ float smemf[];
  float* xs = smemf;                         // 111*112 = 12432 floats
  float* P  = xs + 12432;                    // 111*64  = 7104
  float* U  = P + 7104;                     // 7104
  unsigned* abits = (unsigned*)(U + 7104);   // 111*4 u32
  float* dis0 = (float*)(abits + 444);       // 112
  float* dis1 = dis0 + 112;                  // 112

  const int tid  = threadIdx.x;
  const int lane = tid & 63;
  const int wv   = tid >> 6;    // 0..7
  const int col  = tid & 63;
  const int rg   = tid >> 6;
  const int b    = b0 + blockIdx.x;
  const float* xb = x   + (size_t)b * (NN0 * NN0);
  const float* ab = adj + (size_t)b * (NN0 * NN0);

  for (int idx = tid; idx < NN0 * NN0; idx += 512) {
    int i = idx / NN0;
    int k = idx - i * NN0;
    xs[i * 112 + k] = xb[idx];
  }
  for (int i = wv; i < NN0; i += 8) {
    unsigned long long m0 = __ballot(ab[i * NN0 + lane] != 0.0f);
    float a1 = (64 + lane < NN0) ? ab[i * NN0 + 64 + lane] : 0.0f;
    unsigned long long m1 = __ballot(a1 != 0.0f);
    if (lane == 0) {
      abits[i * 4 + 0] = (unsigned)m0;
      abits[i * 4 + 1] = (unsigned)(m0 >> 32);
      abits[i * 4 + 2] = (unsigned)m1;
      abits[i * 4 + 3] = (unsigned)(m1 >> 32);
      int d = __popcll(m0) + __popcll(m1);
      dis0[i] = (d > 0) ? (1.0f / sqrtf((float)d)) : 0.0f;
      dis1[i] = 1.0f / sqrtf((float)(d + 1));
    }
  }
  __syncthreads();

  // P = xs @ W[:, c0+col]  (W is [111][128] row-major, passed pre-offset by c0+col)
  auto mmP = [&](const float* W) {
    float acc[14];
#pragma unroll
    for (int t = 0; t < 14; ++t) acc[t] = 0.0f;
    for (int kq = 0; kq < 27; ++kq) {
      float w0 = W[(4 * kq + 0) * HD];
      float w1 = W[(4 * kq + 1) * HD];
      float w2 = W[(4 * kq + 2) * HD];
      float w3 = W[(4 * kq + 3) * HD];
#pragma unroll
      for (int t = 0; t < 14; ++t) {
        int r = rg + 8 * t;
        if (r < NN0) {
          float4 xq = *(const float4*)(xs + r * 112 + 4 * kq);
          acc[t] += xq.x * w0 + xq.y * w1 + xq.z * w2 + xq.w * w3;
        }
      }
    }
#pragma unroll
    for (int k = 108; k < 111; ++k) {
      float w0 = W[k * HD];
#pragma unroll
      for (int t = 0; t < 14; ++t) {
        int r = rg + 8 * t;
        if (r < NN0) acc[t] += xs[r * 112 + k] * w0;
      }
    }
#pragma unroll
    for (int t = 0; t < 14; ++t) {
      int r = rg + 8 * t;
      if (r < NN0) P[r * 64 + col] = acc[t];
    }
  };
  // sum over neighbors j of i: coef[j]*buf[j*64+col]
  auto nsum = [&](int i, const float* coef, const float* buf) {
    float acc = 0.0f;
    const unsigned* rb = abits + i * 4;
#pragma unroll
    for (int wd = 0; wd < 4; ++wd) {
      unsigned u = rb[wd];
      while (u) {
        int j = (wd << 5) + __builtin_ctz(u);
        u &= u - 1;
        acc += coef[j] * buf[j * 64 + col];
      }
    }
    return acc;
  };

  float* h1b = h1 + (size_t)blockIdx.x * (NN0 * FD);
  for (int c = 0; c < 2; ++c) {
    int c0 = c * 64;
    // ---- GCN branch
    mmP(wg + c0 + col);
    __syncthreads();
    for (int t = 0; t < 14; ++t) {
      int i = rg + 8 * t;
      if (i < NN0) {
        float acc = dis1[i] * P[i * 64 + col] + nsum(i, dis1, P);
        h1b[i * FD + c0 + col] = fmaxf(dis1[i] * acc, 0.0f);
      }
    }
    __syncthreads();
    // ---- Cheb branch: out = P0 + lh@P1 + 2*lh@(lh@P2) - P2
    float cacc[14];
    mmP(wsp + 2 * (NN0 * HD) + c0 + col);   // P = x@W2
    __syncthreads();
    for (int t = 0; t < 14; ++t) {
      int i = rg + 8 * t;
      if (i < NN0) {
        cacc[t] = -P[i * 64 + col];
        U[i * 64 + col] = -dis0[i] * nsum(i, dis0, P);   // U = lh@P2
      } else cacc[t] = 0.0f;
    }
    __syncthreads();
    for (int t = 0; t < 14; ++t) {
      int i = rg + 8 * t;
      if (i < NN0) cacc[t] += -2.0f * dis0[i] * nsum(i, dis0, U);  // += 2*lh@U
    }
    mmP(wsp + 1 * (NN0 * HD) + c0 + col);   // P = x@W1
    __syncthreads();
    for (int t = 0; t < 14; ++t) {
      int i = rg + 8 * t;
      if (i < NN0) cacc[t] += -dis0[i] * nsum(i, dis0, P);         // += lh@P1
    }
    __syncthreads();
    mmP(wsp + 0 + c0 + col);                // P = x@W0
    __syncthreads();
    for (int t = 0; t < 14; ++t) {
      int i = rg + 8 * t;
      if (i < NN0) {
        float v = cacc[t] + P[i * 64 + col];
        h1b[i * FD + HD + c0 + col] = fmaxf(v, 0.0f);
      }
    }
    __syncthreads();
  }
}

// ---------------------------------------------------------------------------
// K2: pool1. scores (exact f32), stable top-56 rank, gather hp1 + adjp bits,
// readout x1. LDS: hs[111][256] + abits + misc = 116,560 B
// ---------------------------------------------------------------------------
__global__ __launch_bounds__(512) void k_pool1(
    const float* __restrict__ h1, const float* __restrict__ adj,
    float* __restrict__ hp1, unsigned long long* __restrict__ adjp,
    float* __restrict__ x1r, int b0)
{
  extern __shared__ float smemf[];
  float* hs = smemf;                               // 111*256 = 28416
  unsigned* abits = (unsigned*)(hs + 28416);       // 444
  float* dinv = (float*)(abits + 444);             // 112
  float* sc = dinv + 112;                          // 112
  int* sel = (int*)(sc + 112);                     // 56

  const int tid = threadIdx.x, lane = tid & 63, wv = tid >> 6;
  const int bl = blockIdx.x;
  const int b = b0 + bl;
  const float* hb = h1 + (size_t)bl * (NN0 * FD);
  const float* ab = adj + (size_t)b * (NN0 * NN0);

  for (int q = tid; q < NN0 * 64; q += 512)
    ((float4*)hs)[q] = ((const float4*)hb)[q];
  for (int i = wv; i < NN0; i += 8) {
    unsigned long long m0 = __ballot(ab[i * NN0 + lane] != 0.0f);
    float a1 = (64 + lane < NN0) ? ab[i * NN0 + 64 + lane] : 0.0f;
    unsigned long long m1 = __ballot(a1 != 0.0f);
    if (lane == 0) {
      abits[i * 4 + 0] = (unsigned)m0;
      abits[i * 4 + 1] = (unsigned)(m0 >> 32);
      abits[i * 4 + 2] = (unsigned)m1;
      abits[i * 4 + 3] = (unsigned)(m1 >> 32);
      int d = __popcll(m0) + __popcll(m1);
      dinv[i] = (d > 0) ? (1.0f / (float)d) : 0.0f;
    }
  }
  __syncthreads();
  // score[i] = sum_f |h[i][f] - dinv[i]*sum_{j in N(i)} h[j][f]|
  for (int i = wv; i < NN0; i += 8) {
    float nb0 = 0, nb1 = 0, nb2 = 0, nb3 = 0;
    const unsigned* rb = abits + i * 4;
#pragma unroll
    for (int wd = 0; wd < 4; ++wd) {
      unsigned u = rb[wd];
      while (u) {
        int j = (wd << 5) + __builtin_ctz(u);
        u &= u - 1;
        const float* hr = hs + j * FD + lane;
        nb0 += hr[0]; nb1 += hr[64]; nb2 += hr[128]; nb3 += hr[192];
      }
    }
    const float* hi = hs + i * FD + lane;
    float di = dinv[i];
    float s = fabsf(hi[0] - di * nb0) + fabsf(hi[64] - di * nb1)
            + fabsf(hi[128] - di * nb2) + fabsf(hi[192] - di * nb3);
    for (int off = 32; off; off >>= 1) s += __shfl_xor(s, off);
    if (lane == 0) sc[i] = s;
  }
  __syncthreads();
  // stable rank: (score desc, index asc) == jax.lax.top_k order
  if (tid < NN0) {
    float my = sc[tid];
    int cnt = 0;
    for (int j = 0; j < NN0; ++j) {
      float sj = sc[j];
      cnt += (sj > my) || (sj == my && j < tid);
    }
    if (cnt < NN1) sel[cnt] = tid;
  }
  __syncthreads();
  float* hpb = hp1 + (size_t)bl * (NN1 * FD);
  for (int r = wv; r < NN1; r += 8) {
    int i = sel[r];
    const float* hr = hs + i * FD + lane;
    float* dst = hpb + r * FD + lane;
    dst[0] = hr[0]; dst[64] = hr[64]; dst[128] = hr[128]; dst[192] = hr[192];
    int j2 = (lane < NN1) ? sel[lane] : 0;
    bool bit = (lane < NN1) && ((abits[i * 4 + (j2 >> 5)] >> (j2 & 31)) & 1);
    unsigned long long m = __ballot(bit);
    if (lane == 0) adjp[(size_t)bl * NN1 + r] = m;
  }
  __syncthreads();
  if (tid < FD) {
    float mx = -3.402823466e38f, sm = 0.0f;
    for (int r = 0; r < NN1; ++r) {
      float v = hs[sel[r] * FD + tid];
      mx = fmaxf(mx, v); sm += v;
    }
    x1r[(size_t)bl * 512 + tid] = mx;
    x1r[(size_t)bl * 512 + 256 + tid] = sm / 56.0f;
  }
}

// ---------------------------------------------------------------------------
// K3: stage-2 conv on pooled graph (56 nodes, 256 feats). LDS 86,976 B
// ---------------------------------------------------------------------------
__global__ __launch_bounds__(512) void k_stage2(
    const float* __restrict__ hp1, const unsigned long long* __restrict__ adjp,
    const float* __restrict__ wg, const float* __restrict__ wsp,
    float* __restrict__ h2)
{
  extern __shared__ float smemf[];
  float* hs = smemf;                                       // 56*256 = 14336
  float* P  = hs + 14336;                                  // 3584
  float* U  = P + 3584;                                    // 3584
  unsigned long long* rowm = (unsigned long long*)(U + 3584);  // 56 u64
  float* dis0 = (float*)(rowm + 56);                       // 64
  float* dis1 = dis0 + 64;                                 // 64

  const int tid = threadIdx.x, col = tid & 63, rg = tid >> 6;
  const int bl = blockIdx.x;
  const float* hb = hp1 + (size_t)bl * (NN1 * FD);
  for (int q = tid; q < NN1 * 64; q += 512)
    ((float4*)hs)[q] = ((const float4*)hb)[q];
  if (tid < NN1) {
    unsigned long long m = adjp[(size_t)bl * NN1 + tid];
    rowm[tid] = m;
    int d = __popcll(m);
    dis0[tid] = (d > 0) ? (1.0f / sqrtf((float)d)) : 0.0f;
    dis1[tid] = 1.0f / sqrtf((float)(d + 1));
  }
  __syncthreads();

  auto mmP = [&](const float* W) {   // W: [256][128], pre-offset by c0+col
    float acc[7];
#pragma unroll
    for (int t = 0; t < 7; ++t) acc[t] = 0.0f;
    for (int kq = 0; kq < 64; ++kq) {
      float w0 = W[(4 * kq + 0) * HD];
      float w1 = W[(4 * kq + 1) * HD];
      float w2 = W[(4 * kq + 2) * HD];
      float w3 = W[(4 * kq + 3) * HD];
#pragma unroll
      for (int t = 0; t < 7; ++t) {
        int r = rg + 8 * t;
        float4 xq = *(const float4*)(hs + r * FD + 4 * kq);
        acc[t] += xq.x * w0 + xq.y * w1 + xq.z * w2 + xq.w * w3;
      }
    }
#pragma unroll
    for (int t = 0; t < 7; ++t) P[(rg + 8 * t) * 64 + col] = acc[t];
  };
  auto nsum = [&](int i, const float* coef, const float* buf) {
    float acc = 0.0f;
    unsigned long long u = rowm[i];
    while (u) {
      int j = __builtin_ctzll(u);
      u &= u - 1;
      acc += coef[j] * buf[j * 64 + col];
    }
    return acc;
  };

  float* h2b = h2 + (size_t)bl * (NN1 * FD);
  for (int c = 0; c < 2; ++c) {
    int c0 = c * 64;
    mmP(wg + c0 + col);
    __syncthreads();
#pragma unroll
    for (int t = 0; t < 7; ++t) {
      int i = rg + 8 * t;
      float acc = dis1[i] * P[i * 64 + col] + nsum(i, dis1, P);
      h2b[i * FD + c0 + col] = fmaxf(dis1[i] * acc, 0.0f);
    }
    __syncthreads();
    float cacc[7];
    mmP(wsp + 2 * (FD * HD) + c0 + col);
    __syncthreads();
#pragma unroll
    for (int t = 0; t < 7; ++t) {
      int i = rg + 8 * t;
      cacc[t] = -P[i * 64 + col];
      U[i * 64 + col] = -dis0[i] * nsum(i, dis0, P);
    }
    __syncthreads();
#pragma unroll
    for (int t = 0; t < 7; ++t) {
      int i = rg + 8 * t;
      cacc[t] += -2.0f * dis0[i] * nsum(i, dis0, U);
    }
    mmP(wsp + 1 * (FD * HD) + c0 + col);
    __syncthreads();
#pragma unroll
    for (int t = 0; t < 7; ++t) {
      int i = rg + 8 * t;
      cacc[t] += -dis0[i] * nsum(i, dis0, P);
    }
    __syncthreads();
    mmP(wsp + 0 + c0 + col);
    __syncthreads();
#pragma unroll
    for (int t = 0; t < 7; ++t) {
      int i = rg + 8 * t;
      h2b[i * FD + HD + c0 + col] = fmaxf(cacc[t] + P[i * 64 + col], 0.0f);
    }
    __syncthreads();
  }
}

// ---------------------------------------------------------------------------
// K4: pool2 + readout x2 (no adj output needed). LDS 58,432 B
// ---------------------------------------------------------------------------
__global__ __launch_bounds__(256) void k_pool2(
    const float* __restrict__ h2, const unsigned long long* __restrict__ adjp,
    float* __restrict__ hp2, float* __restrict__ x2r)
{
  extern __shared__ float smemf[];
  float* hs = smemf;                                        // 14336
  unsigned long long* rowm = (unsigned long long*)(hs + 14336);  // 56 u64
  float* dinv = (float*)(rowm + 56);  // 64
  float* sc = dinv + 64;              // 64
  int* sel = (int*)(sc + 64);         // 32

  const int tid = threadIdx.x, lane = tid & 63, wv = tid >> 6;
  const int bl = blockIdx.x;
  const float* hb = h2 + (size_t)bl * (NN1 * FD);
  for (int q = tid; q < NN1 * 64; q += 256)
    ((float4*)hs)[q] = ((const float4*)hb)[q];
  if (tid < NN1) {
    unsigned long long m = adjp[(size_t)bl * NN1 + tid];
    rowm[tid] = m;
    int d = __popcll(m);
    dinv[tid] = (d > 0) ? (1.0f / (float)d) : 0.0f;
  }
  __syncthreads();
  for (int i = wv; i < NN1; i += 4) {
    float nb0 = 0, nb1 = 0, nb2 = 0, nb3 = 0;
    unsigned long long u = rowm[i];
    while (u) {
      int j = __builtin_ctzll(u);
      u &= u - 1;
      const float* hr = hs + j * FD + lane;
      nb0 += hr[0]; nb1 += hr[64]; nb2 += hr[128]; nb3 += hr[192];
    }
    const float* hi = hs + i * FD + lane;
    float di = dinv[i];
    float s = fabsf(hi[0] - di * nb0) + fabsf(hi[64] - di * nb1)
            + fabsf(hi[128] - di * nb2) + fabsf(hi[192] - di * nb3);
    for (int off = 32; off; off >>= 1) s += __shfl_xor(s, off);
    if (lane == 0) sc[i] = s;
  }
  __syncthreads();
  if (tid < NN1) {
    float my = sc[tid];
    int cnt = 0;
    for (int j = 0; j < NN1; ++j) {
      float sj = sc[j];
      cnt += (sj > my) || (sj == my && j < tid);
    }
    if (cnt < NN2) sel[cnt] = tid;
  }
  __syncthreads();
  float* hpb = hp2 + (size_t)bl * (NN2 * FD);
  for (int r = wv; r < NN2; r += 4) {
    const float* hr = hs + sel[r] * FD + lane;
    float* dst = hpb + r * FD + lane;
    dst[0] = hr[0]; dst[64] = hr[64]; dst[128] = hr[128]; dst[192] = hr[192];
  }
  {
    float mx = -3.402823466e38f, sm = 0.0f;
    for (int r = 0; r < NN2; ++r) {
      float v = hs[sel[r] * FD + tid];
      mx = fmaxf(mx, v); sm += v;
    }
    x2r[(size_t)bl * 512 + tid] = mx;
    x2r[(size_t)bl * 512 + 256 + tid] = sm / 28.0f;
  }
}

// ---------------------------------------------------------------------------
// K5: f = relu(z @ lin1_w + b1). z assembled on the fly from hp2|x1|x2.
// Tile: 32 graphs x 64 cols, K-block 32. grid (G/32, 4), 256 thr.
// ---------------------------------------------------------------------------
__global__ __launch_bounds__(256) void k_lin1(
    const float* __restrict__ hp2, const float* __restrict__ x1r,
    const float* __restrict__ x2r, const float* __restrict__ w,
    const float* __restrict__ bias, float* __restrict__ fbuf)
{
  __shared__ float zt[32][36];
  __shared__ float wt[32][64];
  const int tid = threadIdx.x, col = tid & 63, rg = tid >> 6;
  const int g0 = blockIdx.x * 32;
  const int n0 = blockIdx.y * 64;
  float acc[8];
#pragma unroll
  for (int t = 0; t < 8; ++t) acc[t] = 0.0f;
  for (int kb = 0; kb < 256; ++kb) {
    int k0 = kb * 32;
#pragma unroll
    for (int q = 0; q < 4; ++q) {
      int e = tid + 256 * q;
      int k = e & 31, m = e >> 5;
      int g = g0 + m, kk = k0 + k;
      float v;
      if (kk < 7168)       v = hp2[(size_t)g * 7168 + kk];
      else if (kk < 7680)  v = x1r[(size_t)g * 512 + (kk - 7168)];
      else                 v = x2r[(size_t)g * 512 + (kk - 7680)];
      zt[m][k] = v;
    }
#pragma unroll
    for (int q = 0; q < 8; ++q) {
      int e = tid + 256 * q;
      int c = e & 63, kr = e >> 6;
      wt[kr][c] = w[(size_t)(k0 + kr) * 256 + n0 + c];
    }
    __syncthreads();
#pragma unroll
    for (int k = 0; k < 32; k += 4) {
      float w0 = wt[k][col], w1 = wt[k + 1][col], w2 = wt[k + 2][col], w3 = wt[k + 3][col];
#pragma unroll
      for (int t = 0; t < 8; ++t) {
        int m = rg * 8 + t;
        float4 zq = *(const float4*)(&zt[m][k]);
        acc[t] += zq.x * w0 + zq.y * w1 + zq.z * w2 + zq.w * w3;
      }
    }
    __syncthreads();
  }
#pragma unroll
  for (int t = 0; t < 8; ++t) {
    int m = rg * 8 + t;
    float v = acc[t] + bias[n0 + col];
    fbuf[(size_t)(g0 + m) * 256 + n0 + col] = fmaxf(v, 0.0f);
  }
}

// ---------------------------------------------------------------------------
// K6: features = relu(f @ lin2_w + b2); x_lo = softmax(features). 128 thr.
// ---------------------------------------------------------------------------
__global__ __launch_bounds__(128) void k_head(
    const float* __restrict__ fbuf, const float* __restrict__ w2,
    const float* __restrict__ b2, float* __restrict__ out, int b0)
{
  __shared__ __align__(16) float fs[256];
  __shared__ float red[2];
  const int tid = threadIdx.x, lane = tid & 63, wv = tid >> 6;
  const int bl = blockIdx.x, b = b0 + bl;
  for (int i = tid; i < 256; i += 128) fs[i] = fbuf[(size_t)bl * 256 + i];
  __syncthreads();
  float acc = b2[tid];
  for (int k = 0; k < 256; k += 4) {
    float4 fq = *(const float4*)(fs + k);
    acc += fq.x * w2[(k + 0) * 128 + tid] + fq.y * w2[(k + 1) * 128 + tid]
         + fq.z * w2[(k + 2) * 128 + tid] + fq.w * w2[(k + 3) * 128 + tid];
  }
  float feat = fmaxf(acc, 0.0f);
  out[(size_t)(NB * 128) + (size_t)b * 128 + tid] = feat;
  float m = feat;
  for (int off = 32; off; off >>= 1) m = fmaxf(m, __shfl_xor(m, off));
  if (lane == 0) red[wv] = m;
  __syncthreads();
  m = fmaxf(red[0], red[1]);
  float e = expf(feat - m);
  float s = e;
  for (int off = 32; off; off >>= 1) s += __shfl_xor(s, off);
  __syncthreads();
  if (lane == 0) red[wv] = s;
  __syncthreads();
  s = red[0] + red[1];
  out[(size_t)b * 128 + tid] = e / s;
}

// ---------------------------------------------------------------------------
extern "C" void kernel_launch(void* const* d_in, const int* in_sizes, int n_in,
                              void* d_out, int out_size, void* d_ws, size_t ws_size,
                              hipStream_t stream) {
  const float* x    = (const float*)d_in[0];
  const float* adj  = (const float*)d_in[1];
  const float* wg1  = (const float*)d_in[2];
  const float* wsp1 = (const float*)d_in[3];
  const float* wg2  = (const float*)d_in[4];
  const float* wsp2 = (const float*)d_in[5];
  const float* l1w  = (const float*)d_in[6];
  const float* l1b  = (const float*)d_in[7];
  const float* l2w  = (const float*)d_in[8];
  const float* l2b  = (const float*)d_in[9];
  float* out = (float*)d_out;

  auto al = [](size_t v) { return (v + 255) & ~(size_t)255; };
  size_t oh1, ohp1, oadjp, ox1, ohp2, ox2, of;
  auto plan = [&](int g) -> size_t {
    size_t o = 0;
    oh1 = o;   o += al((size_t)g * NN0 * FD * 4);   // h1 (also h2 overlay)
    ohp1 = o;  o += al((size_t)g * NN1 * FD * 4);
    oadjp = o; o += al((size_t)g * NN1 * 8);
    ox1 = o;   o += al((size_t)g * 512 * 4);
    ohp2 = o;  o += al((size_t)g * NN2 * FD * 4);
    ox2 = o;   o += al((size_t)g * 512 * 4);
    of = o;    o += al((size_t)g * 256 * 4);
    return o;
  };
  int G = 2048;
  while (G > 64 && plan(G) > ws_size) G >>= 1;
  if (plan(G) > ws_size) return;  // cannot run: leave output wrong (loud fail)

  char* wsb = (char*)d_ws;
  float* h1  = (float*)(wsb + oh1);
  float* hp1 = (float*)(wsb + ohp1);
  unsigned long long* adjp = (unsigned long long*)(wsb + oadjp);
  float* x1r = (float*)(wsb + ox1);
  float* hp2 = (float*)(wsb + ohp2);
  float* x2r = (float*)(wsb + ox2);
  float* fbuf = (float*)(wsb + of);

  const size_t LDS1 = (size_t)(12432 + 7104 + 7104 + 444 + 112 + 112) * 4;    // 109,232
  const size_t LDS2 = (size_t)(28416 + 444 + 112 + 112 + 56) * 4;             // 116,560
  const size_t LDS3 = (size_t)(14336 + 3584 + 3584 + 112 + 64 + 64) * 4;      // 86,976
  const size_t LDS4 = (size_t)(14336 + 112 + 64 + 64 + 32) * 4;               // 58,432

  for (int b0 = 0; b0 < NB; b0 += G) {
    k_stage1<<<G, 512, LDS1, stream>>>(x, adj, wg1, wsp1, h1, b0);
    k_pool1<<<G, 512, LDS2, stream>>>(h1, adj, hp1, adjp, x1r, b0);
    k_stage2<<<G, 512, LDS3, stream>>>(hp1, adjp, wg2, wsp2, h1 /*h2 overlay*/);
    k_pool2<<<G, 256, LDS4, stream>>>(h1, adjp, hp2, x2r);
    k_lin1<<<dim3(G / 32, 4), 256, 0, stream>>>(hp2, x1r, x2r, l1w, l1b, fbuf);
    k_head<<<G, 128, 0, stream>>>(fbuf, l2w, l2b, out, b0);
  }
}